// Round 1
// baseline (857.833 us; speedup 1.0000x reference)
//
#include <hip/hip_runtime.h>
#include <hip/hip_bf16.h>

// KNN k-th smallest distance: dist = sqrt(2 - 2*dot(zn, rn)) after row
// normalization; sorted(dist)[k] == (k+1)-th LARGEST dot. Pipeline:
//  1) normalize_rows: z -> zn, ref -> rn (fp32, in d_ws)
//  2) knn_chunk: tiled dot products + per-chunk per-row top-11 candidates
//  3) knn_final: merge 16 chunks x 11 candidates, take (k+1)-th largest dot

#define D_DIM 128
#define TQ 64          // query rows per block
#define RT 32          // ref rows per sub-tile
#define NCH 16         // ref chunks (grid.y)
#define KK 11          // keep top-11 (k=10 -> need 11th largest)
#define LSTR 132       // padded LDS row stride (floats); %4==0 for float4, +4 breaks 128-stride conflicts

__device__ __forceinline__ void insert11(float (&b)[KK], float v) {
    // b is sorted ascending; b[0] is the smallest of the kept 11.
    if (v > b[0]) {
        b[0] = v;
        #pragma unroll
        for (int i = 0; i < KK - 1; ++i) {
            float lo = fminf(b[i], b[i + 1]);
            float hi = fmaxf(b[i], b[i + 1]);
            b[i] = lo;
            b[i + 1] = hi;
        }
    }
}

__global__ __launch_bounds__(64) void normalize_rows(
    const float* __restrict__ in, float* __restrict__ out)
{
    const size_t row = blockIdx.x;
    const int t = threadIdx.x;
    float a = in[row * D_DIM + t];
    float b = in[row * D_DIM + t + 64];
    float ss = a * a + b * b;
    #pragma unroll
    for (int off = 32; off > 0; off >>= 1)
        ss += __shfl_xor(ss, off);
    const float inv = 1.0f / sqrtf(ss);
    out[row * D_DIM + t] = a * inv;
    out[row * D_DIM + t + 64] = b * inv;
}

__global__ __launch_bounds__(256) void knn_chunk(
    const float* __restrict__ zn, const float* __restrict__ rn,
    float* __restrict__ cand, int N, int M, int chunk)
{
    // LDS: z-tile + r-tile for compute; merge buffer aliases the same space
    // (only used after the compute loop is fully done).
    __shared__ float smem[TQ * LSTR + RT * LSTR];   // 50688 B
    float* zt = smem;
    float* rt = smem + TQ * LSTR;
    float* mrg = smem;                              // alias; needs TQ*88 = 5632 floats

    const int t = threadIdx.x;
    const int qbase = blockIdx.x * TQ;
    const int c0 = blockIdx.y * chunk;
    const int c1 = min(c0 + chunk, M);

    // Load z tile: 64 rows x 32 float4 = 2048 float4, 8 per thread.
    #pragma unroll
    for (int i = 0; i < (TQ * 32) / 256; ++i) {
        int idx = t + 256 * i;
        int row = idx >> 5, dq = idx & 31;
        int zr = qbase + row; if (zr >= N) zr = N - 1;
        const float4 v = *(const float4*)&zn[(size_t)zr * D_DIM + dq * 4];
        *(float4*)&zt[row * LSTR + dq * 4] = v;
    }

    const int rl = t & 7;         // ref lane: refs rl + 8*m, m=0..3
    const int rowA = t >> 3;      // 0..31
    const int rowB = rowA + 32;

    float bestA[KK], bestB[KK];
    #pragma unroll
    for (int i = 0; i < KK; ++i) { bestA[i] = -3.0f; bestB[i] = -3.0f; }

    for (int s0 = c0; s0 < c1; s0 += RT) {
        __syncthreads();   // prior compute done (and, first iter, zt stores visible path below)
        // Load ref sub-tile: 32 rows x 32 float4 = 1024 float4, 4 per thread.
        #pragma unroll
        for (int i = 0; i < (RT * 32) / 256; ++i) {
            int idx = t + 256 * i;
            int r = idx >> 5, dq = idx & 31;
            int g = s0 + r; if (g >= M) g = M - 1;   // clamp; guarded at insert
            const float4 v = *(const float4*)&rn[(size_t)g * D_DIM + dq * 4];
            *(float4*)&rt[r * LSTR + dq * 4] = v;
        }
        __syncthreads();

        float acc[8];
        #pragma unroll
        for (int i = 0; i < 8; ++i) acc[i] = 0.0f;

        #pragma unroll 4
        for (int dq = 0; dq < 32; ++dq) {
            const float4 za = *(const float4*)&zt[rowA * LSTR + dq * 4];
            const float4 zb = *(const float4*)&zt[rowB * LSTR + dq * 4];
            #pragma unroll
            for (int m = 0; m < 4; ++m) {
                const float4 rv = *(const float4*)&rt[(rl + 8 * m) * LSTR + dq * 4];
                acc[m]     += za.x * rv.x + za.y * rv.y + za.z * rv.z + za.w * rv.w;
                acc[4 + m] += zb.x * rv.x + zb.y * rv.y + zb.z * rv.z + zb.w * rv.w;
            }
        }

        #pragma unroll
        for (int m = 0; m < 4; ++m) {
            int g = s0 + rl + 8 * m;
            if (g < c1) {            // strict chunk bound: each ref counted once
                insert11(bestA, acc[m]);
                insert11(bestB, acc[4 + m]);
            }
        }
    }

    __syncthreads();
    // Merge: per row, 8 ref-lanes each hold KK candidates -> mrg[row][rl][KK]
    #pragma unroll
    for (int i = 0; i < KK; ++i) {
        mrg[rowA * (8 * KK) + rl * KK + i] = bestA[i];
        mrg[rowB * (8 * KK) + rl * KK + i] = bestB[i];
    }
    __syncthreads();
    if (t < TQ) {
        float bb[KK];
        #pragma unroll
        for (int i = 0; i < KK; ++i) bb[i] = -3.0f;
        for (int i = 0; i < 8 * KK; ++i) insert11(bb, mrg[t * (8 * KK) + i]);
        const int qr = qbase + t;
        if (qr < N) {
            float* cp = &cand[((size_t)qr * NCH + blockIdx.y) * KK];
            #pragma unroll
            for (int i = 0; i < KK; ++i) cp[i] = bb[i];
        }
    }
}

__global__ __launch_bounds__(64) void knn_final(
    const float* __restrict__ cand, const int* __restrict__ kp,
    float* __restrict__ out)
{
    const int row = blockIdx.x;
    const int t = threadIdx.x;
    const int nc = NCH * KK;   // 176 candidates per row
    float v[3];
    #pragma unroll
    for (int i = 0; i < 3; ++i) {
        int idx = t + 64 * i;
        v[i] = (idx < nc) ? cand[(size_t)row * nc + idx] : -3.0f;
    }
    const int kk = *kp;        // 10
    float cur = -3.0f;
    for (int it = 0; it <= kk; ++it) {
        float m = fmaxf(v[0], fmaxf(v[1], v[2]));
        #pragma unroll
        for (int off = 32; off > 0; off >>= 1)
            m = fmaxf(m, __shfl_xor(m, off));
        cur = m;
        // Remove exactly one instance of the max (lowest lane, lowest slot).
        unsigned long long b0 = __ballot(v[0] == m);
        if (b0) {
            if (__ffsll(b0) - 1 == t) v[0] = -3.0f;
        } else {
            unsigned long long b1 = __ballot(v[1] == m);
            if (b1) {
                if (__ffsll(b1) - 1 == t) v[1] = -3.0f;
            } else {
                unsigned long long b2 = __ballot(v[2] == m);
                if (__ffsll(b2) - 1 == t) v[2] = -3.0f;
            }
        }
    }
    if (t == 0) out[row] = sqrtf(fmaxf(2.0f - 2.0f * cur, 1e-12f));
}

extern "C" void kernel_launch(void* const* d_in, const int* in_sizes, int n_in,
                              void* d_out, int out_size, void* d_ws, size_t ws_size,
                              hipStream_t stream) {
    const float* z   = (const float*)d_in[0];
    const float* ref = (const float*)d_in[1];
    const int*   kp  = (const int*)d_in[2];
    float* out = (float*)d_out;

    const int N = in_sizes[0] / D_DIM;   // 2048
    const int M = in_sizes[1] / D_DIM;   // 50000

    float* zn   = (float*)d_ws;                       // N*128 floats
    float* rn   = zn + (size_t)N * D_DIM;             // M*128 floats
    float* cand = rn + (size_t)M * D_DIM;             // N*NCH*KK floats

    normalize_rows<<<N, 64, 0, stream>>>(z, zn);
    normalize_rows<<<M, 64, 0, stream>>>(ref, rn);

    const int chunk = (M + NCH - 1) / NCH;            // 3125
    dim3 grid((N + TQ - 1) / TQ, NCH);                // 32 x 16 = 512 blocks
    knn_chunk<<<grid, 256, 0, stream>>>(zn, rn, cand, N, M, chunk);

    knn_final<<<N, 64, 0, stream>>>(cand, kp, out);
}

// Round 2
// 236.678 us; speedup vs baseline: 3.6245x; 3.6245x over previous
//
#include <hip/hip_runtime.h>

// KNN k-th smallest distance, MFMA version.
// dist = sqrt(2 - 2*dot(zn,rn)); sorted(dist)[k] == (k+1)-th LARGEST dot.
// 1) normalize_bf16: fp32 rows -> L2-normalized bf16 rows (z and ref)
// 2) knn_mfma: bf16 MFMA dot tiles (16x16x32) + fused per-row top-11
// 3) knn_final: merge NCH chunks x 11 candidates, take (k+1)-th largest dot
//
// Accuracy: bf16 rounding perturbs each dot by ~3.5e-4; k-th order statistic
// is 1-Lipschitz in that perturbation -> dist error ~3e-4 << 2.39e-2 threshold.

#define D_DIM 128
#define TQ 64          // queries per block (4 waves x 16 rows)
#define BR 128         // refs per block iteration
#define NCH 16         // ref chunks (grid.y)
#define KK 11          // top-11 (k=10 -> 11th largest)
#define ASTR 136       // LDS row stride (bf16 elems); 272B: 16B-aligned, 2-way banks max

typedef __bf16 bf16_t;
typedef bf16_t bf16x8 __attribute__((ext_vector_type(8)));
typedef float f32x4 __attribute__((ext_vector_type(4)));

__device__ __forceinline__ unsigned short f2bf(float f) {
    unsigned u = __float_as_uint(f);
    return (unsigned short)((u + 0x7fffu + ((u >> 16) & 1u)) >> 16);  // RNE
}

__device__ __forceinline__ void insert11(float (&b)[KK], float v) {
    // b sorted ascending; b[0] is the 11th-largest so far.
    if (v > b[0]) {
        b[0] = v;
        #pragma unroll
        for (int i = 0; i < KK - 1; ++i) {
            float lo = fminf(b[i], b[i + 1]);
            float hi = fmaxf(b[i], b[i + 1]);
            b[i] = lo;
            b[i + 1] = hi;
        }
    }
}

__global__ __launch_bounds__(256) void normalize_bf16(
    const float* __restrict__ in, unsigned short* __restrict__ out, int nrows)
{
    const int w = threadIdx.x >> 6;
    const int l = threadIdx.x & 63;
    const int row = blockIdx.x * 4 + w;
    if (row >= nrows) return;
    const float2 v = ((const float2*)in)[(size_t)row * 64 + l];
    float ss = v.x * v.x + v.y * v.y;
    #pragma unroll
    for (int off = 32; off > 0; off >>= 1) ss += __shfl_xor(ss, off);
    const float inv = rsqrtf(ss);
    ushort2 o; o.x = f2bf(v.x * inv); o.y = f2bf(v.y * inv);
    ((ushort2*)out)[(size_t)row * 64 + l] = o;
}

__global__ __launch_bounds__(256) void knn_mfma(
    const unsigned short* __restrict__ zb, const unsigned short* __restrict__ rb,
    float* __restrict__ cand, int N, int M, int chunk)
{
    // A-tile + B-tile for compute; merge buffer aliases (used only after loop).
    __shared__ __align__(16) union {
        struct { unsigned short At[TQ * ASTR]; unsigned short Bt[BR * ASTR]; } s;
        float mrg[TQ * 16 * KK];   // 45056 B <= 52224 B
    } u;

    const int t = threadIdx.x;
    const int lane = t & 63;
    const int w = t >> 6;          // wave -> query rows w*16..w*16+15
    const int quad = lane >> 4;
    const int ln = lane & 15;
    const int qbase = blockIdx.x * TQ;
    const int c0 = blockIdx.y * chunk;
    const int c1 = min(c0 + chunk, M);

    // Stage A tile: 64 rows x 16 chunks(16B) = 1024, 4 per thread.
    #pragma unroll
    for (int i = 0; i < (TQ * 16) / 256; ++i) {
        int idx = t + 256 * i;
        int r = idx >> 4, c = idx & 15;
        const uint4 v = *(const uint4*)&zb[(size_t)(qbase + r) * D_DIM + c * 8];
        *(uint4*)&u.s.At[r * ASTR + c * 8] = v;
    }
    __syncthreads();

    // A fragments: constant for the whole chunk loop (K=128 = 4 MFMA K-steps).
    bf16x8 afr[4];
    #pragma unroll
    for (int ks = 0; ks < 4; ++ks)
        afr[ks] = *(const bf16x8*)&u.s.At[(w * 16 + ln) * ASTR + ks * 32 + quad * 8];

    float best[4][KK];   // per-lane top-11 for query rows quad*4+r
    #pragma unroll
    for (int r = 0; r < 4; ++r)
        #pragma unroll
        for (int i = 0; i < KK; ++i) best[r][i] = -3.0f;

    for (int s0 = c0; s0 < c1; s0 += BR) {
        __syncthreads();   // prior iteration's B-frag reads done
        // Stage B tile: 128 refs x 16 chunks = 2048, 8 per thread. Coalesced 16B.
        #pragma unroll
        for (int i = 0; i < (BR * 16) / 256; ++i) {
            int idx = t + 256 * i;
            int r = idx >> 4, c = idx & 15;
            int g = s0 + r; if (g > M - 1) g = M - 1;   // clamp; excluded at insert
            const uint4 v = *(const uint4*)&rb[(size_t)g * D_DIM + c * 8];
            *(uint4*)&u.s.Bt[r * ASTR + c * 8] = v;
        }
        __syncthreads();

        f32x4 acc[8];
        #pragma unroll
        for (int ct = 0; ct < 8; ++ct) acc[ct] = (f32x4){0.f, 0.f, 0.f, 0.f};

        // ks outer so the 8 col-tiles' MFMAs are independent (pipelined).
        #pragma unroll
        for (int ks = 0; ks < 4; ++ks) {
            #pragma unroll
            for (int ct = 0; ct < 8; ++ct) {
                bf16x8 bfr = *(const bf16x8*)
                    &u.s.Bt[(ct * 16 + ln) * ASTR + ks * 32 + quad * 8];
                acc[ct] = __builtin_amdgcn_mfma_f32_16x16x32_bf16(
                    afr[ks], bfr, acc[ct], 0, 0, 0);
            }
        }

        // Epilogue: lane holds col (ref) = s0+ct*16+ln, rows quad*4+r.
        #pragma unroll
        for (int ct = 0; ct < 8; ++ct) {
            int g = s0 + ct * 16 + ln;
            if (g < c1) {
                #pragma unroll
                for (int r = 0; r < 4; ++r) insert11(best[r], acc[ct][r]);
            }
        }
    }

    __syncthreads();
    // Dump per-lane lists: query-local row ql = w*16+quad*4+r, source id = ln.
    #pragma unroll
    for (int r = 0; r < 4; ++r) {
        int ql = w * 16 + quad * 4 + r;
        #pragma unroll
        for (int i = 0; i < KK; ++i)
            u.mrg[(ql * 16 + ln) * KK + i] = best[r][i];
    }
    __syncthreads();

    // Stage-1 merge: thread (ql = t>>2, gg = t&3) merges sources gg*4..gg*4+3
    // in-place into slot gg*4 (only this thread touches that group).
    {
        int ql = t >> 2, gg = t & 3;
        float bb[KK];
        #pragma unroll
        for (int i = 0; i < KK; ++i) bb[i] = -3.0f;
        for (int n = gg * 4; n < gg * 4 + 4; ++n)
            for (int i = 0; i < KK; ++i) insert11(bb, u.mrg[(ql * 16 + n) * KK + i]);
        __syncthreads();   // all reads done before in-place overwrite
        #pragma unroll
        for (int i = 0; i < KK; ++i) u.mrg[(ql * 16 + gg * 4) * KK + i] = bb[i];
    }
    __syncthreads();

    // Stage-2 merge: thread t<64 merges the 4 group results for its row.
    if (t < TQ) {
        float bb[KK];
        #pragma unroll
        for (int i = 0; i < KK; ++i) bb[i] = -3.0f;
        #pragma unroll
        for (int gg = 0; gg < 4; ++gg)
            for (int i = 0; i < KK; ++i)
                insert11(bb, u.mrg[(t * 16 + gg * 4) * KK + i]);
        float* cp = &cand[((size_t)(qbase + t) * NCH + blockIdx.y) * KK];
        #pragma unroll
        for (int i = 0; i < KK; ++i) cp[i] = bb[i];
    }
}

__global__ __launch_bounds__(64) void knn_final(
    const float* __restrict__ cand, const int* __restrict__ kp,
    float* __restrict__ out)
{
    const int row = blockIdx.x;
    const int t = threadIdx.x;
    const int nc = NCH * KK;   // 176 candidates per row
    float v[3];
    #pragma unroll
    for (int i = 0; i < 3; ++i) {
        int idx = t + 64 * i;
        v[i] = (idx < nc) ? cand[(size_t)row * nc + idx] : -3.0f;
    }
    const int kk = *kp;        // 10
    float cur = -3.0f;
    for (int it = 0; it <= kk; ++it) {
        float m = fmaxf(v[0], fmaxf(v[1], v[2]));
        #pragma unroll
        for (int off = 32; off > 0; off >>= 1)
            m = fmaxf(m, __shfl_xor(m, off));
        cur = m;
        unsigned long long b0 = __ballot(v[0] == m);
        if (b0) {
            if (__ffsll(b0) - 1 == t) v[0] = -3.0f;
        } else {
            unsigned long long b1 = __ballot(v[1] == m);
            if (b1) {
                if (__ffsll(b1) - 1 == t) v[1] = -3.0f;
            } else {
                unsigned long long b2 = __ballot(v[2] == m);
                if (__ffsll(b2) - 1 == t) v[2] = -3.0f;
            }
        }
    }
    if (t == 0) out[row] = sqrtf(fmaxf(2.0f - 2.0f * cur, 1e-12f));
}

extern "C" void kernel_launch(void* const* d_in, const int* in_sizes, int n_in,
                              void* d_out, int out_size, void* d_ws, size_t ws_size,
                              hipStream_t stream) {
    const float* z   = (const float*)d_in[0];
    const float* ref = (const float*)d_in[1];
    const int*   kp  = (const int*)d_in[2];
    float* out = (float*)d_out;

    const int N = in_sizes[0] / D_DIM;   // 2048
    const int M = in_sizes[1] / D_DIM;   // 50000

    unsigned short* zbuf = (unsigned short*)d_ws;                 // N*128 bf16
    unsigned short* rbuf = zbuf + (size_t)N * D_DIM;              // M*128 bf16
    float* cand = (float*)(rbuf + (size_t)M * D_DIM);             // N*NCH*KK f32

    normalize_bf16<<<(N + 3) / 4, 256, 0, stream>>>(z, zbuf, N);
    normalize_bf16<<<(M + 3) / 4, 256, 0, stream>>>(ref, rbuf, M);

    const int chunk = (M + NCH - 1) / NCH;            // 3125
    dim3 grid(N / TQ, NCH);                           // 32 x 16 = 512 blocks
    knn_mfma<<<grid, 256, 0, stream>>>(zbuf, rbuf, cand, N, M, chunk);

    knn_final<<<N, 64, 0, stream>>>(cand, kp, out);
}

// Round 3
// 176.050 us; speedup vs baseline: 4.8727x; 1.3444x over previous
//
#include <hip/hip_runtime.h>

// KNN k-th smallest distance, two-pass threshold-filter MFMA version.
// dist = sqrt(2 - 2*dot(zn,rn)); sorted(dist)[k] == (k+1)-th LARGEST dot.
//  1) normalize_bf16: fused z+ref rows -> L2-normalized bf16
//  2) knn_pass<1>:  MFMA dots, epilogue = per-(row,chunk,lane16) subset MAX
//     (subsets partition the refs -> 11th largest of subset maxes is a valid
//      lower bound T on the true 11th-largest dot)
//  3) knn_threshold: per row, exact 11th-largest of 768 subset maxes -> T;
//     zeroes survivor counters
//  4) knn_pass<2>:  MFMA dots again, keep v >= T[row] via atomic append
//     (~15-40 survivors/row; top-11 guaranteed among them)
//  5) knn_final: exact 11th-largest of survivors -> dist
//
// Accuracy: bf16 rounding perturbs each dot by ~3.5e-4; the k-th order
// statistic is 1-Lipschitz in that perturbation -> << 2.39e-2 threshold.

#define D_DIM 128
#define TQ 128         // queries per block (4 waves x 2 row-tiles x 16 rows)
#define BR 64          // refs per block iteration
#define NCH 48         // ref chunks (grid.y); 16*48=768 blocks, 3/CU
#define NSUB (NCH * 16) // subsets per row = 768
#define KK 11          // need 11th largest (k=10)
#define CAP 256        // survivor capacity per row
#define ASTR 136       // LDS row stride (bf16); 272B: 16B-aligned, conflict-benign

typedef __bf16 bf16_t;
typedef bf16_t bf16x8 __attribute__((ext_vector_type(8)));
typedef float f32x4 __attribute__((ext_vector_type(4)));

__device__ __forceinline__ unsigned short f2bf(float f) {
    unsigned u = __float_as_uint(f);
    return (unsigned short)((u + 0x7fffu + ((u >> 16) & 1u)) >> 16);  // RNE
}

__global__ __launch_bounds__(256) void normalize_bf16(
    const float* __restrict__ z, const float* __restrict__ ref,
    unsigned short* __restrict__ zb, unsigned short* __restrict__ rb,
    int N, int M)
{
    const int w = threadIdx.x >> 6;
    const int l = threadIdx.x & 63;
    const int row = blockIdx.x * 4 + w;
    if (row >= N + M) return;
    const float* in; unsigned short* out; int r;
    if (row < N) { in = z;   out = zb; r = row; }
    else         { in = ref; out = rb; r = row - N; }
    const float2 v = ((const float2*)in)[(size_t)r * 64 + l];
    float ss = v.x * v.x + v.y * v.y;
    #pragma unroll
    for (int off = 32; off > 0; off >>= 1) ss += __shfl_xor(ss, off);
    const float inv = rsqrtf(ss);
    ushort2 o; o.x = f2bf(v.x * inv); o.y = f2bf(v.y * inv);
    ((ushort2*)out)[(size_t)r * 64 + l] = o;
}

// PASS==1: write subset maxes.  PASS==2: filter vs T, append survivors.
template <int PASS>
__global__ __launch_bounds__(256, 3) void knn_pass(
    const unsigned short* __restrict__ zb, const unsigned short* __restrict__ rb,
    float* __restrict__ maxes, const float* __restrict__ T,
    int* __restrict__ cnt, float* __restrict__ surv,
    int N, int M, int chunk)
{
    __shared__ __align__(16) unsigned short At[TQ * ASTR];  // 34816 B
    __shared__ __align__(16) unsigned short Bt[BR * ASTR];  // 17408 B

    const int t = threadIdx.x;
    const int lane = t & 63;
    const int w = t >> 6;          // wave -> query rows w*32 .. w*32+31
    const int quad = lane >> 4;
    const int ln = lane & 15;
    const int qbase = blockIdx.x * TQ;
    const int c0 = blockIdx.y * chunk;
    const int c1 = min(c0 + chunk, M);

    // Stage A tile: 128 rows x 16 x 16B = 2048 uint4, 8 per thread.
    #pragma unroll
    for (int i = 0; i < (TQ * 16) / 256; ++i) {
        int idx = t + 256 * i;
        int r = idx >> 4, c = idx & 15;
        *(uint4*)&At[r * ASTR + c * 8] =
            *(const uint4*)&zb[(size_t)(qbase + r) * D_DIM + c * 8];
    }
    __syncthreads();

    // A fragments: rows w*32 + rt*16 + ln, constant across the chunk loop.
    bf16x8 afr[2][4];
    #pragma unroll
    for (int rt = 0; rt < 2; ++rt)
        #pragma unroll
        for (int ks = 0; ks < 4; ++ks)
            afr[rt][ks] = *(const bf16x8*)
                &At[(w * 32 + rt * 16 + ln) * ASTR + ks * 32 + quad * 8];

    float mx[2][4];   // pass1: per-lane subset max, rows rt*16+quad*4+r
    float tr[2][4];   // pass2: per-row thresholds
    if (PASS == 1) {
        #pragma unroll
        for (int rt = 0; rt < 2; ++rt)
            #pragma unroll
            for (int r = 0; r < 4; ++r) mx[rt][r] = -3.0f;
    } else {
        #pragma unroll
        for (int rt = 0; rt < 2; ++rt)
            #pragma unroll
            for (int r = 0; r < 4; ++r)
                tr[rt][r] = T[qbase + w * 32 + rt * 16 + quad * 4 + r];
    }

    for (int s0 = c0; s0 < c1; s0 += BR) {
        __syncthreads();   // prior tile's B-frag reads done
        // Stage B tile: 64 refs x 16 x 16B = 1024 uint4, 4 per thread.
        #pragma unroll
        for (int i = 0; i < (BR * 16) / 256; ++i) {
            int idx = t + 256 * i;
            int r = idx >> 4, c = idx & 15;
            int g = s0 + r; if (g > M - 1) g = M - 1;   // clamp; excluded below
            *(uint4*)&Bt[r * ASTR + c * 8] =
                *(const uint4*)&rb[(size_t)g * D_DIM + c * 8];
        }
        __syncthreads();

        f32x4 acc[2][4];
        #pragma unroll
        for (int rt = 0; rt < 2; ++rt)
            #pragma unroll
            for (int ct = 0; ct < 4; ++ct) acc[rt][ct] = (f32x4){0.f,0.f,0.f,0.f};

        #pragma unroll
        for (int ks = 0; ks < 4; ++ks) {
            #pragma unroll
            for (int ct = 0; ct < 4; ++ct) {
                bf16x8 bfr = *(const bf16x8*)
                    &Bt[(ct * 16 + ln) * ASTR + ks * 32 + quad * 8];
                #pragma unroll
                for (int rt = 0; rt < 2; ++rt)
                    acc[rt][ct] = __builtin_amdgcn_mfma_f32_16x16x32_bf16(
                        afr[rt][ks], bfr, acc[rt][ct], 0, 0, 0);
            }
        }

        // Epilogue. Lane's column g is uniform across rt/r for fixed ct.
        #pragma unroll
        for (int ct = 0; ct < 4; ++ct) {
            int g = s0 + ct * 16 + ln;
            if (g < c1) {
                if (PASS == 1) {
                    #pragma unroll
                    for (int rt = 0; rt < 2; ++rt)
                        #pragma unroll
                        for (int r = 0; r < 4; ++r)
                            mx[rt][r] = fmaxf(mx[rt][r], acc[rt][ct][r]);
                } else {
                    #pragma unroll
                    for (int rt = 0; rt < 2; ++rt)
                        #pragma unroll
                        for (int r = 0; r < 4; ++r) {
                            float v = acc[rt][ct][r];
                            if (v >= tr[rt][r]) {   // rare
                                int row = qbase + w * 32 + rt * 16 + quad * 4 + r;
                                int slot = atomicAdd(&cnt[row], 1);
                                if (slot < CAP) surv[(size_t)row * CAP + slot] = v;
                            }
                        }
                }
            }
        }
    }

    if (PASS == 1) {
        #pragma unroll
        for (int rt = 0; rt < 2; ++rt)
            #pragma unroll
            for (int r = 0; r < 4; ++r) {
                int row = qbase + w * 32 + rt * 16 + quad * 4 + r;
                maxes[(size_t)row * NSUB + blockIdx.y * 16 + ln] = mx[rt][r];
            }
    }
}

__global__ __launch_bounds__(64) void knn_threshold(
    const float* __restrict__ maxes, const int* __restrict__ kp,
    float* __restrict__ T, int* __restrict__ cnt)
{
    const int row = blockIdx.x;
    const int t = threadIdx.x;
    float v[NSUB / 64];   // 12
    #pragma unroll
    for (int i = 0; i < NSUB / 64; ++i)
        v[i] = maxes[(size_t)row * NSUB + t + 64 * i];
    const int kk = *kp;   // 10
    float cur = -3.0f;
    for (int it = 0; it <= kk; ++it) {
        float m = v[0];
        #pragma unroll
        for (int i = 1; i < NSUB / 64; ++i) m = fmaxf(m, v[i]);
        #pragma unroll
        for (int off = 32; off > 0; off >>= 1) m = fmaxf(m, __shfl_xor(m, off));
        cur = m;
        bool done = false;   // wave-uniform (derived from ballot)
        for (int i = 0; i < NSUB / 64 && !done; ++i) {
            unsigned long long b = __ballot(v[i] == m);
            if (b) {
                if ((int)(__ffsll(b) - 1) == t) v[i] = -3.0f;
                done = true;
            }
        }
    }
    if (t == 0) { T[row] = cur; cnt[row] = 0; }
}

__global__ __launch_bounds__(64) void knn_final(
    const float* __restrict__ surv, const int* __restrict__ cnt,
    const int* __restrict__ kp, float* __restrict__ out)
{
    const int row = blockIdx.x;
    const int t = threadIdx.x;
    int c = cnt[row]; if (c > CAP) c = CAP;
    float v[CAP / 64];   // 4
    #pragma unroll
    for (int i = 0; i < CAP / 64; ++i) {
        int idx = t + 64 * i;
        v[i] = (idx < c) ? surv[(size_t)row * CAP + idx] : -3.0f;
    }
    const int kk = *kp;
    float cur = -3.0f;
    for (int it = 0; it <= kk; ++it) {
        float m = v[0];
        #pragma unroll
        for (int i = 1; i < CAP / 64; ++i) m = fmaxf(m, v[i]);
        #pragma unroll
        for (int off = 32; off > 0; off >>= 1) m = fmaxf(m, __shfl_xor(m, off));
        cur = m;
        bool done = false;
        for (int i = 0; i < CAP / 64 && !done; ++i) {
            unsigned long long b = __ballot(v[i] == m);
            if (b) {
                if ((int)(__ffsll(b) - 1) == t) v[i] = -3.0f;
                done = true;
            }
        }
    }
    if (t == 0) out[row] = sqrtf(fmaxf(2.0f - 2.0f * cur, 1e-12f));
}

extern "C" void kernel_launch(void* const* d_in, const int* in_sizes, int n_in,
                              void* d_out, int out_size, void* d_ws, size_t ws_size,
                              hipStream_t stream) {
    const float* z   = (const float*)d_in[0];
    const float* ref = (const float*)d_in[1];
    const int*   kp  = (const int*)d_in[2];
    float* out = (float*)d_out;

    const int N = in_sizes[0] / D_DIM;   // 2048
    const int M = in_sizes[1] / D_DIM;   // 50000

    unsigned short* zbuf = (unsigned short*)d_ws;             // N*128 bf16
    unsigned short* rbuf = zbuf + (size_t)N * D_DIM;          // M*128 bf16
    float* maxes = (float*)(rbuf + (size_t)M * D_DIM);        // N*NSUB f32 (4MB)
    float* T     = maxes + (size_t)N * NSUB;                  // N f32
    int*   cnt   = (int*)(T + N);                             // N i32
    float* surv  = (float*)(cnt + N);                         // N*CAP f32 (2MB)

    normalize_bf16<<<(N + M + 3) / 4, 256, 0, stream>>>(z, ref, zbuf, rbuf, N, M);

    const int chunk = (M + NCH - 1) / NCH;    // 1042
    dim3 grid(N / TQ, NCH);                   // 16 x 48 = 768 blocks

    knn_pass<1><<<grid, 256, 0, stream>>>(zbuf, rbuf, maxes, nullptr,
                                          nullptr, nullptr, N, M, chunk);
    knn_threshold<<<N, 64, 0, stream>>>(maxes, kp, T, cnt);
    knn_pass<2><<<grid, 256, 0, stream>>>(zbuf, rbuf, nullptr, T,
                                          cnt, surv, N, M, chunk);
    knn_final<<<N, 64, 0, stream>>>(surv, cnt, kp, out);
}